// Round 1
// baseline (368.456 us; speedup 1.0000x reference)
//
#include <hip/hip_runtime.h>
#include <hip/hip_bf16.h>

#define DIM   1024
#define NHEAD 16
#define HDIM  64
#define BATCH 4
#define SEQ   1024
#define MTOT  (BATCH*SEQ)   // 4096
#define DFF   (4*DIM)       // 4096

typedef _Float16 f16x8 __attribute__((ext_vector_type(8)));
typedef _Float16 f16x4 __attribute__((ext_vector_type(4)));
typedef float    f32x4 __attribute__((ext_vector_type(4)));

__device__ __forceinline__ float geluf(float x) {
    float x3 = x * x * x;
    return 0.5f * x * (1.0f + tanhf(0.7978845608028654f * (x + 0.044715f * x3)));
}

// Swizzled LDS byte offset for tiles with 64-f16 (128 B) rows, 8 slots of 16 B.
// XOR of slot with (row&7) breaks the stride-128B 16-way bank conflict (G4).
__device__ __forceinline__ int swz_off(int row, int slot) {
    return row * 128 + ((slot ^ (row & 7)) << 4);
}

__device__ __forceinline__ f16x8 ldsfrag(const _Float16* s, int row, int slot) {
    return *(const f16x8*)((const char*)s + swz_off(row, slot));
}

// ---------------- transpose + fp32->f16 convert:  src[K][N] -> dst[N][K] ----
__global__ __launch_bounds__(256) void k_tcvt(const float* __restrict__ src,
                                              _Float16* __restrict__ dst,
                                              int K, int N) {
    __shared__ float tile[32][33];
    int n0 = blockIdx.x * 32, k0 = blockIdx.y * 32;
    int tx = threadIdx.x, ty = threadIdx.y;
#pragma unroll
    for (int i = 0; i < 32; i += 8)
        tile[ty + i][tx] = src[(size_t)(k0 + ty + i) * N + (n0 + tx)];
    __syncthreads();
#pragma unroll
    for (int i = 0; i < 32; i += 8)
        dst[(size_t)(n0 + ty + i) * K + (k0 + tx)] = (_Float16)tile[tx][ty + i];
}

// ---------------- LayerNorm (fp32 in -> f16 out), one block per row, D=1024 -
__global__ __launch_bounds__(256) void k_ln(const float* __restrict__ x,
                                            const float* __restrict__ sc,
                                            const float* __restrict__ sh,
                                            _Float16* __restrict__ out) {
    int row = blockIdx.x;
    int t = threadIdx.x;
    float4 v = ((const float4*)(x + (size_t)row * DIM))[t];
    float sum = v.x + v.y + v.z + v.w;
    float sq  = v.x * v.x + v.y * v.y + v.z * v.z + v.w * v.w;
#pragma unroll
    for (int m = 1; m < 64; m <<= 1) {
        sum += __shfl_xor(sum, m);
        sq  += __shfl_xor(sq, m);
    }
    __shared__ float rs[4], rq[4];
    int w = t >> 6;
    if ((t & 63) == 0) { rs[w] = sum; rq[w] = sq; }
    __syncthreads();
    sum = rs[0] + rs[1] + rs[2] + rs[3];
    sq  = rq[0] + rq[1] + rq[2] + rq[3];
    float mean = sum * (1.0f / DIM);
    float var  = sq * (1.0f / DIM) - mean * mean;
    float rstd = rsqrtf(var + 1e-5f);
    float4 s4 = ((const float4*)sc)[t];
    float4 b4 = ((const float4*)sh)[t];
    f16x4 o;
    o[0] = (_Float16)(s4.x * ((v.x - mean) * rstd) + b4.x);
    o[1] = (_Float16)(s4.y * ((v.y - mean) * rstd) + b4.y);
    o[2] = (_Float16)(s4.z * ((v.z - mean) * rstd) + b4.z);
    o[3] = (_Float16)(s4.w * ((v.w - mean) * rstd) + b4.w);
    ((f16x4*)(out + (size_t)row * DIM))[t] = o;
}

// ---------------- GEMM: C[M,N] = A[M,K] * BT[N,K]^T, f16 in, fp32 acc -------
// 128x128 tile, BK=64, 256 threads (4 waves 2x2), 16x16x32 f16 MFMA.
__device__ __forceinline__ void stage_tile(const _Float16* __restrict__ g, int ld,
                                           _Float16* s, int t) {
    int r0 = t >> 3;      // 0..31
    int slot = t & 7;     // 0..7 (16B chunks of a 128B row)
#pragma unroll
    for (int q = 0; q < 4; ++q) {
        int row = r0 + q * 32;
        int4 v = *(const int4*)(g + (size_t)row * ld + slot * 8);
        *(int4*)((char*)s + swz_off(row, slot)) = v;
    }
}

// EPI: 0 = plain -> f16 out; 1 = +bias, gelu -> f16 out; 2 = +bias +resid -> f32 out
template <int EPI>
__global__ __launch_bounds__(256) void k_gemm(const _Float16* __restrict__ A,
                                              const _Float16* __restrict__ BT,
                                              int M, int N, int K,
                                              float* __restrict__ Cf,
                                              _Float16* __restrict__ Ch,
                                              const float* __restrict__ bias,
                                              const float* __restrict__ resid) {
    __shared__ _Float16 As[128 * 64];
    __shared__ _Float16 Bs[128 * 64];
    int t = threadIdx.x;
    int m0 = blockIdx.y * 128, n0 = blockIdx.x * 128;
    int lane = t & 63, w = t >> 6;
    int wm = (w >> 1) * 64, wn = (w & 1) * 64;
    int lr = lane & 15, lg = lane >> 4;
    f32x4 acc[4][4];
#pragma unroll
    for (int i = 0; i < 4; ++i)
#pragma unroll
        for (int j = 0; j < 4; ++j) acc[i][j] = (f32x4){0.f, 0.f, 0.f, 0.f};

    const _Float16* Ag = A  + (size_t)m0 * K;
    const _Float16* Bg = BT + (size_t)n0 * K;
    for (int k0 = 0; k0 < K; k0 += 64) {
        stage_tile(Ag + k0, K, As, t);
        stage_tile(Bg + k0, K, Bs, t);
        __syncthreads();
#pragma unroll
        for (int kk = 0; kk < 2; ++kk) {
            f16x8 a[4], b[4];
#pragma unroll
            for (int i = 0; i < 4; ++i) a[i] = ldsfrag(As, wm + i * 16 + lr, kk * 4 + lg);
#pragma unroll
            for (int j = 0; j < 4; ++j) b[j] = ldsfrag(Bs, wn + j * 16 + lr, kk * 4 + lg);
#pragma unroll
            for (int i = 0; i < 4; ++i)
#pragma unroll
                for (int j = 0; j < 4; ++j)
                    acc[i][j] = __builtin_amdgcn_mfma_f32_16x16x32_f16(a[i], b[j], acc[i][j], 0, 0, 0);
        }
        __syncthreads();
    }
    // epilogue; C/D frag: col = lane&15, row = (lane>>4)*4 + r  [m89-verified]
#pragma unroll
    for (int i = 0; i < 4; ++i) {
#pragma unroll
        for (int j = 0; j < 4; ++j) {
            int row = m0 + wm + i * 16 + lg * 4;
            int col = n0 + wn + j * 16 + lr;
#pragma unroll
            for (int r = 0; r < 4; ++r) {
                float v = acc[i][j][r];
                size_t idx = (size_t)(row + r) * N + col;
                if constexpr (EPI == 0) {
                    Ch[idx] = (_Float16)v;
                } else if constexpr (EPI == 1) {
                    Ch[idx] = (_Float16)geluf(v + bias[col]);
                } else {
                    Cf[idx] = v + bias[col] + resid[idx];
                }
            }
        }
    }
}

// ---------------- Flash attention: 1 wave per (b, h, 64-row q-tile) ---------
__global__ __launch_bounds__(64) void k_attn(const _Float16* __restrict__ Qg,
                                             const _Float16* __restrict__ Kg,
                                             const _Float16* __restrict__ Vg,
                                             _Float16* __restrict__ Og) {
    __shared__ _Float16 Ps[64 * 64];  // P[q][k], swizzled 128B rows
    __shared__ _Float16 Vt[64 * 64];  // V^T [d][k], swizzled
    int lane = threadIdx.x;
    int qt = blockIdx.x, h = blockIdx.y, b = blockIdx.z;
    int q0 = qt * 64;
    int lr = lane & 15, lg = lane >> 4;
    size_t base = (size_t)b * SEQ;
    int cb = h * HDIM;

    // Q fragments in registers (A-operand: row=lane&15, k=(lane>>4)*8+e)
    f16x8 aq[4][2];
#pragma unroll
    for (int i = 0; i < 4; ++i)
#pragma unroll
        for (int kk = 0; kk < 2; ++kk)
            aq[i][kk] = *(const f16x8*)(Qg + (base + q0 + i * 16 + lr) * DIM + cb + kk * 32 + lg * 8);

    f32x4 cacc[4][4];
#pragma unroll
    for (int i = 0; i < 4; ++i)
#pragma unroll
        for (int j = 0; j < 4; ++j) cacc[i][j] = (f32x4){0.f, 0.f, 0.f, 0.f};
    float mrun[4][4], lrun[4][4];
#pragma unroll
    for (int i = 0; i < 4; ++i)
#pragma unroll
        for (int r = 0; r < 4; ++r) { mrun[i][r] = -1e30f; lrun[i][r] = 0.f; }

    for (int kt = 0; kt <= qt; ++kt) {
        int k0 = kt * 64;
        // stage V^T into LDS (scalar transposed writes, swizzled)
        {
            const _Float16* vr = Vg + (base + k0 + lane) * DIM + cb;
            int kslot = lane >> 3;
            int kb2 = (lane & 7) * 2;
#pragma unroll
            for (int part = 0; part < 8; ++part) {
                f16x8 v8 = *(const f16x8*)(vr + part * 8);
#pragma unroll
                for (int e = 0; e < 8; ++e) {
                    int d = part * 8 + e;
                    *(_Float16*)((char*)Vt + d * 128 + ((kslot ^ (d & 7)) << 4) + kb2) = v8[e];
                }
            }
        }
        // scores = Q K^T (K rows read straight from global; B-op needs K[kcol][:])
        f32x4 sacc[4][4];
#pragma unroll
        for (int i = 0; i < 4; ++i)
#pragma unroll
            for (int j = 0; j < 4; ++j) sacc[i][j] = (f32x4){0.f, 0.f, 0.f, 0.f};
#pragma unroll
        for (int kk = 0; kk < 2; ++kk) {
            f16x8 bk[4];
#pragma unroll
            for (int j = 0; j < 4; ++j)
                bk[j] = *(const f16x8*)(Kg + (base + k0 + j * 16 + lr) * DIM + cb + kk * 32 + lg * 8);
#pragma unroll
            for (int i = 0; i < 4; ++i)
#pragma unroll
                for (int j = 0; j < 4; ++j)
                    sacc[i][j] = __builtin_amdgcn_mfma_f32_16x16x32_f16(aq[i][kk], bk[j], sacc[i][j], 0, 0, 0);
        }
        // scale + causal mask (diagonal tile only)
        bool diag = (kt == qt);
#pragma unroll
        for (int i = 0; i < 4; ++i)
#pragma unroll
            for (int j = 0; j < 4; ++j)
#pragma unroll
                for (int r = 0; r < 4; ++r) {
                    float s = sacc[i][j][r] * 0.125f;  // 1/sqrt(64)
                    if (diag) {
                        int qq = i * 16 + lg * 4 + r;
                        int kc = j * 16 + lr;
                        if (kc > qq) s = -1e30f;
                    }
                    sacc[i][j][r] = s;
                }
        // online softmax (rows spread over 16 lanes -> shfl_xor reduce)
#pragma unroll
        for (int i = 0; i < 4; ++i) {
            float mn[4], al[4];
#pragma unroll
            for (int r = 0; r < 4; ++r) {
                float tm = fmaxf(fmaxf(sacc[i][0][r], sacc[i][1][r]),
                                 fmaxf(sacc[i][2][r], sacc[i][3][r]));
#pragma unroll
                for (int msk = 1; msk < 16; msk <<= 1) tm = fmaxf(tm, __shfl_xor(tm, msk));
                float m2 = fmaxf(mrun[i][r], tm);
                al[r] = __expf(mrun[i][r] - m2);
                mrun[i][r] = m2;
                mn[r] = m2;
            }
#pragma unroll
            for (int jd = 0; jd < 4; ++jd)
#pragma unroll
                for (int r = 0; r < 4; ++r) cacc[i][jd][r] *= al[r];
#pragma unroll
            for (int r = 0; r < 4; ++r) {
                float ps = 0.f;
#pragma unroll
                for (int j = 0; j < 4; ++j) {
                    float p = __expf(sacc[i][j][r] - mn[r]);
                    sacc[i][j][r] = p;
                    ps += p;
                }
#pragma unroll
                for (int msk = 1; msk < 16; msk <<= 1) ps += __shfl_xor(ps, msk);
                lrun[i][r] = lrun[i][r] * al[r] + ps;
            }
        }
        __syncthreads();  // Vt staged & visible
        // write P (f16) to LDS in A-operand-friendly row-major (swizzled)
#pragma unroll
        for (int i = 0; i < 4; ++i)
#pragma unroll
            for (int j = 0; j < 4; ++j) {
                int kc = j * 16 + lr;
                int ks = kc >> 3;
                int kb = (kc & 7) * 2;
#pragma unroll
                for (int r = 0; r < 4; ++r) {
                    int qq = i * 16 + lg * 4 + r;
                    *(_Float16*)((char*)Ps + qq * 128 + ((ks ^ (qq & 7)) << 4) + kb) =
                        (_Float16)sacc[i][j][r];
                }
            }
        __syncthreads();
        // PV accumulate
#pragma unroll
        for (int kk = 0; kk < 2; ++kk) {
            f16x8 pa[4], bv[4];
#pragma unroll
            for (int i = 0; i < 4; ++i)  pa[i]  = ldsfrag(Ps, i * 16 + lr,  kk * 4 + lg);
#pragma unroll
            for (int jd = 0; jd < 4; ++jd) bv[jd] = ldsfrag(Vt, jd * 16 + lr, kk * 4 + lg);
#pragma unroll
            for (int i = 0; i < 4; ++i)
#pragma unroll
                for (int jd = 0; jd < 4; ++jd)
                    cacc[i][jd] = __builtin_amdgcn_mfma_f32_16x16x32_f16(pa[i], bv[jd], cacc[i][jd], 0, 0, 0);
        }
        __syncthreads();  // before next tile overwrites Vt/Ps
    }
    // normalize + write ctx in [b*S+s][h*64+d] layout
#pragma unroll
    for (int i = 0; i < 4; ++i)
#pragma unroll
        for (int jd = 0; jd < 4; ++jd)
#pragma unroll
            for (int r = 0; r < 4; ++r) {
                int qq = q0 + i * 16 + lg * 4 + r;
                int d = cb + jd * 16 + lr;
                Og[(base + qq) * DIM + d] = (_Float16)(cacc[i][jd][r] / lrun[i][r]);
            }
}

// ---------------------------------------------------------------------------
extern "C" void kernel_launch(void* const* d_in, const int* in_sizes, int n_in,
                              void* d_out, int out_size, void* d_ws, size_t ws_size,
                              hipStream_t stream) {
    const float* x    = (const float*)d_in[0];
    const float* WQ   = (const float*)d_in[1];
    const float* WK   = (const float*)d_in[2];
    const float* WV   = (const float*)d_in[3];
    const float* Wo   = (const float*)d_in[4];
    const float* bo   = (const float*)d_in[5];
    const float* W1   = (const float*)d_in[6];
    const float* b1   = (const float*)d_in[7];
    const float* W2   = (const float*)d_in[8];
    const float* b2   = (const float*)d_in[9];
    const float* ln1s = (const float*)d_in[10];
    const float* ln1b = (const float*)d_in[11];
    const float* ln2s = (const float*)d_in[12];
    const float* ln2b = (const float*)d_in[13];
    float* out = (float*)d_out;
    char* ws = (char*)d_ws;
    const size_t MB = 1024 * 1024;
    _Float16* WTq = (_Float16*)(ws + 0 * MB);
    _Float16* WTk = (_Float16*)(ws + 2 * MB);
    _Float16* WTv = (_Float16*)(ws + 4 * MB);
    _Float16* WTo = (_Float16*)(ws + 6 * MB);
    _Float16* WT1 = (_Float16*)(ws + 8 * MB);    // [4096][1024]
    _Float16* WT2 = (_Float16*)(ws + 16 * MB);   // [1024][4096]
    _Float16* h1  = (_Float16*)(ws + 24 * MB);
    _Float16* qb  = (_Float16*)(ws + 32 * MB);
    _Float16* kb  = (_Float16*)(ws + 40 * MB);
    _Float16* vb  = (_Float16*)(ws + 48 * MB);
    _Float16* ctx = (_Float16*)(ws + 56 * MB);
    _Float16* h2  = (_Float16*)(ws + 64 * MB);
    _Float16* ff1 = (_Float16*)(ws + 72 * MB);   // [4096][4096] f16 = 32MB
    float*    x2  = (float*)   (ws + 104 * MB);  // fp32 residual = 16MB; total 120MB

    dim3 tb(32, 8);
    k_tcvt<<<dim3(32, 32), tb, 0, stream>>>(WQ, WTq, 1024, 1024);
    k_tcvt<<<dim3(32, 32), tb, 0, stream>>>(WK, WTk, 1024, 1024);
    k_tcvt<<<dim3(32, 32), tb, 0, stream>>>(WV, WTv, 1024, 1024);
    k_tcvt<<<dim3(32, 32), tb, 0, stream>>>(Wo, WTo, 1024, 1024);
    k_tcvt<<<dim3(128, 32), tb, 0, stream>>>(W1, WT1, 1024, 4096);
    k_tcvt<<<dim3(32, 128), tb, 0, stream>>>(W2, WT2, 4096, 1024);

    k_ln<<<MTOT, 256, 0, stream>>>(x, ln1s, ln1b, h1);

    k_gemm<0><<<dim3(8, 32), 256, 0, stream>>>(h1, WTq, MTOT, DIM, DIM, nullptr, qb, nullptr, nullptr);
    k_gemm<0><<<dim3(8, 32), 256, 0, stream>>>(h1, WTk, MTOT, DIM, DIM, nullptr, kb, nullptr, nullptr);
    k_gemm<0><<<dim3(8, 32), 256, 0, stream>>>(h1, WTv, MTOT, DIM, DIM, nullptr, vb, nullptr, nullptr);

    k_attn<<<dim3(SEQ / 64, NHEAD, BATCH), 64, 0, stream>>>(qb, kb, vb, ctx);

    // x2 = x + ctx @ Wo + bo
    k_gemm<2><<<dim3(8, 32), 256, 0, stream>>>(ctx, WTo, MTOT, DIM, DIM, x2, nullptr, bo, x);

    k_ln<<<MTOT, 256, 0, stream>>>(x2, ln2s, ln2b, h2);

    // ff1 = gelu(h2 @ W1 + b1)
    k_gemm<1><<<dim3(32, 32), 256, 0, stream>>>(h2, WT1, MTOT, DFF, DIM, nullptr, ff1, b1, nullptr);

    // out = x2 + ff1 @ W2 + b2
    k_gemm<2><<<dim3(8, 32), 256, 0, stream>>>(ff1, WT2, MTOT, DIM, DFF, out, nullptr, b2, x2);
}

// Round 3
// 350.947 us; speedup vs baseline: 1.0499x; 1.0499x over previous
//
#include <hip/hip_runtime.h>
#include <hip/hip_bf16.h>

#define DIM   1024
#define NHEAD 16
#define HDIM  64
#define BATCH 4
#define SEQ   1024
#define MTOT  (BATCH*SEQ)   // 4096
#define DFF   (4*DIM)       // 4096
#define LDQ   3072          // fused QKV row stride

typedef _Float16 f16x8 __attribute__((ext_vector_type(8)));
typedef _Float16 f16x4 __attribute__((ext_vector_type(4)));
typedef float    f32x4 __attribute__((ext_vector_type(4)));

__device__ __forceinline__ float geluf(float x) {
    float x3 = x * x * x;
    return 0.5f * x * (1.0f + tanhf(0.7978845608028654f * (x + 0.044715f * x3)));
}

// Swizzled LDS byte offset for tiles with 64-f16 (128 B) rows, 8 slots of 16 B.
__device__ __forceinline__ int swz_off(int row, int slot) {
    return row * 128 + ((slot ^ (row & 7)) << 4);
}
__device__ __forceinline__ f16x8 ldsfrag(const _Float16* s, int row, int slot) {
    return *(const f16x8*)((const char*)s + swz_off(row, slot));
}

// Async global->LDS staging: linear LDS dest (wave-uniform base + lane*16),
// inverse-swizzled GLOBAL source so stored layout == swizzled layout (m173).
template <int NCHUNK>
__device__ __forceinline__ void stage_async(const _Float16* __restrict__ g, int ld,
                                            _Float16* s, int w, int lane) {
    int r_in = lane >> 3;               // 0..7 row within chunk
    int sslot = lane & 7;               // stored 16B slot
    int lslot = sslot ^ r_in;           // logical slot (row&7 == r_in)
#pragma unroll
    for (int q = 0; q < NCHUNK; ++q) {
        int chunk = w * NCHUNK + q;
        int row = chunk * 8 + r_in;
        const _Float16* gp = g + (size_t)row * ld + lslot * 8;
        _Float16* sp = s + chunk * 512;  // wave-uniform
        __builtin_amdgcn_global_load_lds(
            (const __attribute__((address_space(1))) void*)gp,
            (__attribute__((address_space(3))) void*)sp, 16, 0, 0);
    }
}

// ---------------- transpose + fp32->f16 convert:  src[K][N] -> dst[N][K] ----
__global__ __launch_bounds__(256) void k_tcvt(const float* __restrict__ src,
                                              _Float16* __restrict__ dst,
                                              int K, int N) {
    __shared__ float tile[32][33];
    int n0 = blockIdx.x * 32, k0 = blockIdx.y * 32;
    int tx = threadIdx.x, ty = threadIdx.y;
#pragma unroll
    for (int i = 0; i < 32; i += 8)
        tile[ty + i][tx] = src[(size_t)(k0 + ty + i) * N + (n0 + tx)];
    __syncthreads();
#pragma unroll
    for (int i = 0; i < 32; i += 8)
        dst[(size_t)(n0 + ty + i) * K + (k0 + tx)] = (_Float16)tile[tx][ty + i];
}

// ---------------- LayerNorm (fp32 in -> f16 out), one block per row ---------
__global__ __launch_bounds__(256) void k_ln(const float* __restrict__ x,
                                            const float* __restrict__ sc,
                                            const float* __restrict__ sh,
                                            _Float16* __restrict__ out) {
    int row = blockIdx.x;
    int t = threadIdx.x;
    float4 v = ((const float4*)(x + (size_t)row * DIM))[t];
    float sum = v.x + v.y + v.z + v.w;
    float sq  = v.x * v.x + v.y * v.y + v.z * v.z + v.w * v.w;
#pragma unroll
    for (int m = 1; m < 64; m <<= 1) {
        sum += __shfl_xor(sum, m);
        sq  += __shfl_xor(sq, m);
    }
    __shared__ float rs[4], rq[4];
    int w = t >> 6;
    if ((t & 63) == 0) { rs[w] = sum; rq[w] = sq; }
    __syncthreads();
    sum = rs[0] + rs[1] + rs[2] + rs[3];
    sq  = rq[0] + rq[1] + rq[2] + rq[3];
    float mean = sum * (1.0f / DIM);
    float var  = sq * (1.0f / DIM) - mean * mean;
    float rstd = rsqrtf(var + 1e-5f);
    float4 s4 = ((const float4*)sc)[t];
    float4 b4 = ((const float4*)sh)[t];
    f16x4 o;
    o[0] = (_Float16)(s4.x * ((v.x - mean) * rstd) + b4.x);
    o[1] = (_Float16)(s4.y * ((v.y - mean) * rstd) + b4.y);
    o[2] = (_Float16)(s4.z * ((v.z - mean) * rstd) + b4.z);
    o[3] = (_Float16)(s4.w * ((v.w - mean) * rstd) + b4.w);
    ((f16x4*)(out + (size_t)row * DIM))[t] = o;
}

// ---------------- GEMM 128x128, BK=64, async-LDS staged ---------------------
// EPI: 0 = plain -> f16 out; 1 = +bias, gelu -> f16 out
template <int EPI>
__global__ __launch_bounds__(256) void k_gemm(const _Float16* __restrict__ A,
                                              const _Float16* __restrict__ BT,
                                              int M, int N, int K,
                                              _Float16* __restrict__ Ch,
                                              const float* __restrict__ bias) {
    __shared__ _Float16 As[128 * 64];
    __shared__ _Float16 Bs[128 * 64];
    int t = threadIdx.x;
    int m0 = blockIdx.y * 128, n0 = blockIdx.x * 128;
    int lane = t & 63, w = t >> 6;
    int wm = (w >> 1) * 64, wn = (w & 1) * 64;
    int lr = lane & 15, lg = lane >> 4;
    f32x4 acc[4][4];
#pragma unroll
    for (int i = 0; i < 4; ++i)
#pragma unroll
        for (int j = 0; j < 4; ++j) acc[i][j] = (f32x4){0.f, 0.f, 0.f, 0.f};

    const _Float16* Ag = A  + (size_t)m0 * K;
    const _Float16* Bg = BT + (size_t)n0 * K;
    for (int k0 = 0; k0 < K; k0 += 64) {
        stage_async<4>(Ag + k0, K, As, w, lane);
        stage_async<4>(Bg + k0, K, Bs, w, lane);
        __syncthreads();
#pragma unroll
        for (int kk = 0; kk < 2; ++kk) {
            f16x8 a[4], b[4];
#pragma unroll
            for (int i = 0; i < 4; ++i) a[i] = ldsfrag(As, wm + i * 16 + lr, kk * 4 + lg);
#pragma unroll
            for (int j = 0; j < 4; ++j) b[j] = ldsfrag(Bs, wn + j * 16 + lr, kk * 4 + lg);
#pragma unroll
            for (int i = 0; i < 4; ++i)
#pragma unroll
                for (int j = 0; j < 4; ++j)
                    acc[i][j] = __builtin_amdgcn_mfma_f32_16x16x32_f16(a[i], b[j], acc[i][j], 0, 0, 0);
        }
        __syncthreads();
    }
#pragma unroll
    for (int i = 0; i < 4; ++i) {
#pragma unroll
        for (int j = 0; j < 4; ++j) {
            int row = m0 + wm + i * 16 + lg * 4;
            int col = n0 + wn + j * 16 + lr;
#pragma unroll
            for (int r = 0; r < 4; ++r) {
                float v = acc[i][j][r];
                size_t idx = (size_t)(row + r) * N + col;
                if constexpr (EPI == 0) Ch[idx] = (_Float16)v;
                else                    Ch[idx] = (_Float16)geluf(v + bias[col]);
            }
        }
    }
}

// ---------------- GEMM 128x64 tile (for N=1024 outputs), +bias+resid f32 ----
__global__ __launch_bounds__(256) void k_gemm64(const _Float16* __restrict__ A,
                                                const _Float16* __restrict__ BT,
                                                int M, int N, int K,
                                                float* __restrict__ Cf,
                                                const float* __restrict__ bias,
                                                const float* __restrict__ resid) {
    __shared__ _Float16 As[128 * 64];
    __shared__ _Float16 Bs[64 * 64];
    int t = threadIdx.x;
    int m0 = blockIdx.y * 128, n0 = blockIdx.x * 64;
    int lane = t & 63, w = t >> 6;
    int wm = w * 32;
    int lr = lane & 15, lg = lane >> 4;
    f32x4 acc[2][4];
#pragma unroll
    for (int i = 0; i < 2; ++i)
#pragma unroll
        for (int j = 0; j < 4; ++j) acc[i][j] = (f32x4){0.f, 0.f, 0.f, 0.f};

    const _Float16* Ag = A  + (size_t)m0 * K;
    const _Float16* Bg = BT + (size_t)n0 * K;
    for (int k0 = 0; k0 < K; k0 += 64) {
        stage_async<4>(Ag + k0, K, As, w, lane);
        stage_async<2>(Bg + k0, K, Bs, w, lane);
        __syncthreads();
#pragma unroll
        for (int kk = 0; kk < 2; ++kk) {
            f16x8 a[2], b[4];
#pragma unroll
            for (int i = 0; i < 2; ++i) a[i] = ldsfrag(As, wm + i * 16 + lr, kk * 4 + lg);
#pragma unroll
            for (int j = 0; j < 4; ++j) b[j] = ldsfrag(Bs, j * 16 + lr, kk * 4 + lg);
#pragma unroll
            for (int i = 0; i < 2; ++i)
#pragma unroll
                for (int j = 0; j < 4; ++j)
                    acc[i][j] = __builtin_amdgcn_mfma_f32_16x16x32_f16(a[i], b[j], acc[i][j], 0, 0, 0);
        }
        __syncthreads();
    }
#pragma unroll
    for (int i = 0; i < 2; ++i) {
#pragma unroll
        for (int j = 0; j < 4; ++j) {
            int row = m0 + wm + i * 16 + lg * 4;
            int col = n0 + j * 16 + lr;
#pragma unroll
            for (int r = 0; r < 4; ++r) {
                size_t idx = (size_t)(row + r) * N + col;
                Cf[idx] = acc[i][j][r] + bias[col] + resid[idx];
            }
        }
    }
}

// ---------------- Flash attention: 4 waves/block, split over kt tiles -------
// Block = (qt, h, b); wave w handles kt = w, w+4, ... <= qt with per-wave LDS.
// NO barriers in the main loop; barrier-gated merge at the end.
__global__ __launch_bounds__(256) void k_attn(const _Float16* __restrict__ QKV,
                                              _Float16* __restrict__ Og) {
    __shared__ _Float16 VtA[4][4096];  // per-wave V^T, swizzled
    __shared__ _Float16 PsA[4][4096];  // per-wave P, swizzled
    __shared__ float mlb[4 * 128];     // dedicated merge scratch (m, l per wave)
    __shared__ float fin[2 * 64];      // final M, 1/L
    int t = threadIdx.x;
    int lane = t & 63, w = t >> 6;
    int qt = blockIdx.x, h = blockIdx.y, b = blockIdx.z;
    int q0 = qt * 64;
    int lr = lane & 15, lg = lane >> 4;
    size_t base = (size_t)b * SEQ;
    int cq = h * HDIM, ck = 1024 + h * HDIM, cv = 2048 + h * HDIM;
    _Float16* Vt = &VtA[w][0];
    _Float16* Ps = &PsA[w][0];
    float* Cm = (float*)&PsA[0][0];    // [64][64] f32 merge buffer (after barrier)

    // Q fragments in registers, pre-scaled by 1/sqrt(HD)
    f16x8 aq[4][2];
#pragma unroll
    for (int i = 0; i < 4; ++i)
#pragma unroll
        for (int kk = 0; kk < 2; ++kk) {
            f16x8 v = *(const f16x8*)(QKV + (base + q0 + i * 16 + lr) * LDQ + cq + kk * 32 + lg * 8);
#pragma unroll
            for (int e = 0; e < 8; ++e) v[e] = v[e] * (_Float16)0.125f;
            aq[i][kk] = v;
        }

    f32x4 cacc[4][4];
#pragma unroll
    for (int i = 0; i < 4; ++i)
#pragma unroll
        for (int j = 0; j < 4; ++j) cacc[i][j] = (f32x4){0.f, 0.f, 0.f, 0.f};
    float mrun[4][4], lrun[4][4];
#pragma unroll
    for (int i = 0; i < 4; ++i)
#pragma unroll
        for (int r = 0; r < 4; ++r) { mrun[i][r] = -1e30f; lrun[i][r] = 0.f; }

    for (int kt = w; kt <= qt; kt += 4) {
        int k0 = kt * 64;
        // stage V^T into per-wave LDS (swizzled; conflict-free writes)
        {
            const _Float16* vr = QKV + (base + k0 + lane) * LDQ + cv;
            int kslot = lane >> 3;
            int kb2 = (lane & 7) * 2;
#pragma unroll
            for (int part = 0; part < 8; ++part) {
                f16x8 v8 = *(const f16x8*)(vr + part * 8);
#pragma unroll
                for (int e = 0; e < 8; ++e) {
                    int d = part * 8 + e;
                    *(_Float16*)((char*)Vt + d * 128 + ((kslot ^ (d & 7)) << 4) + kb2) = v8[e];
                }
            }
        }
        // scores = Q K^T (K fragments straight from global, L2-hot)
        f32x4 sacc[4][4];
#pragma unroll
        for (int i = 0; i < 4; ++i)
#pragma unroll
            for (int j = 0; j < 4; ++j) sacc[i][j] = (f32x4){0.f, 0.f, 0.f, 0.f};
#pragma unroll
        for (int kk = 0; kk < 2; ++kk) {
            f16x8 bk[4];
#pragma unroll
            for (int j = 0; j < 4; ++j)
                bk[j] = *(const f16x8*)(QKV + (base + k0 + j * 16 + lr) * LDQ + ck + kk * 32 + lg * 8);
#pragma unroll
            for (int i = 0; i < 4; ++i)
#pragma unroll
                for (int j = 0; j < 4; ++j)
                    sacc[i][j] = __builtin_amdgcn_mfma_f32_16x16x32_f16(aq[i][kk], bk[j], sacc[i][j], 0, 0, 0);
        }
        // causal mask (diagonal tile only; Q pre-scaled)
        if (kt == qt) {
#pragma unroll
            for (int i = 0; i < 4; ++i)
#pragma unroll
                for (int j = 0; j < 4; ++j)
#pragma unroll
                    for (int r = 0; r < 4; ++r) {
                        int qq = i * 16 + lg * 4 + r;
                        int kc = j * 16 + lr;
                        if (kc > qq) sacc[i][j][r] = -1e30f;
                    }
        }
        // online softmax (rows spread over 16 lanes)
#pragma unroll
        for (int i = 0; i < 4; ++i) {
            float mn[4], al[4];
#pragma unroll
            for (int r = 0; r < 4; ++r) {
                float tm = fmaxf(fmaxf(sacc[i][0][r], sacc[i][1][r]),
                                 fmaxf(sacc[i][2][r], sacc[i][3][r]));
#pragma unroll
                for (int msk = 1; msk < 16; msk <<= 1) tm = fmaxf(tm, __shfl_xor(tm, msk));
                float m2 = fmaxf(mrun[i][r], tm);
                al[r] = __expf(mrun[i][r] - m2);
                mrun[i][r] = m2;
                mn[r] = m2;
            }
#pragma unroll
            for (int jd = 0; jd < 4; ++jd)
#pragma unroll
                for (int r = 0; r < 4; ++r) cacc[i][jd][r] *= al[r];
#pragma unroll
            for (int r = 0; r < 4; ++r) {
                float ps = 0.f;
#pragma unroll
                for (int j = 0; j < 4; ++j) {
                    float p = __expf(sacc[i][j][r] - mn[r]);
                    sacc[i][j][r] = p;
                    ps += p;
                }
#pragma unroll
                for (int msk = 1; msk < 16; msk <<= 1) ps += __shfl_xor(ps, msk);
                lrun[i][r] = lrun[i][r] * al[r] + ps;
            }
        }
        // P -> per-wave LDS (f16, swizzled A-operand layout)
#pragma unroll
        for (int i = 0; i < 4; ++i)
#pragma unroll
            for (int j = 0; j < 4; ++j) {
                int kc = j * 16 + lr;
                int ks = kc >> 3;
                int kb = (kc & 7) * 2;
#pragma unroll
                for (int r = 0; r < 4; ++r) {
                    int qq = i * 16 + lg * 4 + r;
                    *(_Float16*)((char*)Ps + qq * 128 + ((ks ^ (qq & 7)) << 4) + kb) =
                        (_Float16)sacc[i][j][r];
                }
            }
        // PV accumulate (same-wave LDS RAW; in-order per-wave DS pipe)
#pragma unroll
        for (int kk = 0; kk < 2; ++kk) {
            f16x8 pa[4], bv[4];
#pragma unroll
            for (int i = 0; i < 4; ++i)   pa[i]  = ldsfrag(Ps, i * 16 + lr,  kk * 4 + lg);
#pragma unroll
            for (int jd = 0; jd < 4; ++jd) bv[jd] = ldsfrag(Vt, jd * 16 + lr, kk * 4 + lg);
#pragma unroll
            for (int i = 0; i < 4; ++i)
#pragma unroll
                for (int jd = 0; jd < 4; ++jd)
                    cacc[i][jd] = __builtin_amdgcn_mfma_f32_16x16x32_f16(pa[i], bv[jd], cacc[i][jd], 0, 0, 0);
        }
    }

    // ---- merge 4 waves' partials ----
    // CRITICAL: all waves must be fully done with their main loop (LDS + regs)
    // before ANY merge scratch is written — waves finish at different times.
    __syncthreads();
    if (lr == 0) {
#pragma unroll
        for (int i = 0; i < 4; ++i)
#pragma unroll
            for (int r = 0; r < 4; ++r) {
                int row = i * 16 + lg * 4 + r;
                mlb[w * 128 + row] = mrun[i][r];
                mlb[w * 128 + 64 + row] = lrun[i][r];
            }
    }
    __syncthreads();
    if (w == 0) {
        float M = -1e30f;
#pragma unroll
        for (int ww = 0; ww < 4; ++ww) M = fmaxf(M, mlb[ww * 128 + lane]);
        float L = 0.f;
#pragma unroll
        for (int ww = 0; ww < 4; ++ww)
            L += mlb[ww * 128 + 64 + lane] * __expf(mlb[ww * 128 + lane] - M);
        fin[lane] = M;
        fin[64 + lane] = 1.0f / L;
    }
    __syncthreads();
    for (int ww = 0; ww < 4; ++ww) {
        if (w == ww) {
#pragma unroll
            for (int i = 0; i < 4; ++i)
#pragma unroll
                for (int r = 0; r < 4; ++r) {
                    int row = i * 16 + lg * 4 + r;
                    float sc = __expf(mrun[i][r] - fin[row]);
#pragma unroll
                    for (int jd = 0; jd < 4; ++jd) {
                        int col = jd * 16 + lr;
                        float v = cacc[i][jd][r] * sc;
                        if (ww == 0) Cm[row * 64 + col] = v;
                        else         Cm[row * 64 + col] += v;
                    }
                }
        }
        __syncthreads();
    }
#pragma unroll
    for (int rr = 0; rr < 16; ++rr) {
        int row = w * 16 + rr;
        float v = Cm[row * 64 + lane] * fin[64 + row];
        Og[(base + q0 + row) * DIM + h * HDIM + lane] = (_Float16)v;
    }
}

// ---------------------------------------------------------------------------
extern "C" void kernel_launch(void* const* d_in, const int* in_sizes, int n_in,
                              void* d_out, int out_size, void* d_ws, size_t ws_size,
                              hipStream_t stream) {
    const float* x    = (const float*)d_in[0];
    const float* WQ   = (const float*)d_in[1];
    const float* WK   = (const float*)d_in[2];
    const float* WV   = (const float*)d_in[3];
    const float* Wo   = (const float*)d_in[4];
    const float* bo   = (const float*)d_in[5];
    const float* W1   = (const float*)d_in[6];
    const float* b1   = (const float*)d_in[7];
    const float* W2   = (const float*)d_in[8];
    const float* b2   = (const float*)d_in[9];
    const float* ln1s = (const float*)d_in[10];
    const float* ln1b = (const float*)d_in[11];
    const float* ln2s = (const float*)d_in[12];
    const float* ln2b = (const float*)d_in[13];
    float* out = (float*)d_out;
    char* ws = (char*)d_ws;
    const size_t MB = 1024 * 1024;
    _Float16* WTqkv = (_Float16*)(ws + 0 * MB);   // [3072][1024] = 6MB
    _Float16* WTo   = (_Float16*)(ws + 6 * MB);
    _Float16* WT1   = (_Float16*)(ws + 8 * MB);   // [4096][1024]
    _Float16* WT2   = (_Float16*)(ws + 16 * MB);  // [1024][4096]
    _Float16* h1    = (_Float16*)(ws + 24 * MB);
    _Float16* qkvb  = (_Float16*)(ws + 32 * MB);  // [4096][3072] = 24MB
    _Float16* ctx   = (_Float16*)(ws + 56 * MB);
    _Float16* h2    = (_Float16*)(ws + 64 * MB);
    _Float16* ff1   = (_Float16*)(ws + 72 * MB);  // [4096][4096] = 32MB
    float*    x2    = (float*)   (ws + 104 * MB); // fp32 residual = 16MB

    dim3 tb(32, 8);
    k_tcvt<<<dim3(32, 32), tb, 0, stream>>>(WQ, WTqkv, 1024, 1024);
    k_tcvt<<<dim3(32, 32), tb, 0, stream>>>(WK, WTqkv + 1024 * 1024, 1024, 1024);
    k_tcvt<<<dim3(32, 32), tb, 0, stream>>>(WV, WTqkv + 2048 * 1024, 1024, 1024);
    k_tcvt<<<dim3(32, 32), tb, 0, stream>>>(Wo, WTo, 1024, 1024);
    k_tcvt<<<dim3(128, 32), tb, 0, stream>>>(W1, WT1, 1024, 4096);
    k_tcvt<<<dim3(32, 128), tb, 0, stream>>>(W2, WT2, 4096, 1024);

    k_ln<<<MTOT, 256, 0, stream>>>(x, ln1s, ln1b, h1);

    // fused QKV: [4096,1024] x [1024,3072] -> [4096,3072]
    k_gemm<0><<<dim3(24, 32), 256, 0, stream>>>(h1, WTqkv, MTOT, LDQ, DIM, qkvb, nullptr);

    k_attn<<<dim3(SEQ / 64, NHEAD, BATCH), 256, 0, stream>>>(qkvb, ctx);

    // x2 = x + ctx @ Wo + bo
    k_gemm64<<<dim3(16, 32), 256, 0, stream>>>(ctx, WTo, MTOT, DIM, DIM, x2, bo, x);

    k_ln<<<MTOT, 256, 0, stream>>>(x2, ln2s, ln2b, h2);

    // ff1 = gelu(h2 @ W1 + b1)
    k_gemm<1><<<dim3(32, 32), 256, 0, stream>>>(h2, WT1, MTOT, DFF, DIM, ff1, b1);

    // out = x2 + ff1 @ W2 + b2
    k_gemm64<<<dim3(16, 32), 256, 0, stream>>>(ff1, WT2, MTOT, DIM, DFF, out, b2, x2);
}

// Round 4
// 293.373 us; speedup vs baseline: 1.2559x; 1.1963x over previous
//
#include <hip/hip_runtime.h>
#include <hip/hip_bf16.h>

#define DIM   1024
#define NHEAD 16
#define HDIM  64
#define BATCH 4
#define SEQ   1024
#define MTOT  (BATCH*SEQ)   // 4096
#define DFF   (4*DIM)       // 4096
#define LDQ   3072          // fused QKV row stride

typedef _Float16 f16x8 __attribute__((ext_vector_type(8)));
typedef _Float16 f16x4 __attribute__((ext_vector_type(4)));
typedef float    f32x4 __attribute__((ext_vector_type(4)));

__device__ __forceinline__ float geluf(float x) {
    float x3 = x * x * x;
    return 0.5f * x * (1.0f + tanhf(0.7978845608028654f * (x + 0.044715f * x3)));
}

// Swizzled LDS byte offset for tiles with 64-f16 (128 B) rows, 8 slots of 16 B.
__device__ __forceinline__ int swz_off(int row, int slot) {
    return row * 128 + ((slot ^ (row & 7)) << 4);
}
__device__ __forceinline__ f16x8 ldsfrag(const _Float16* s, int row, int slot) {
    return *(const f16x8*)((const char*)s + swz_off(row, slot));
}

// Async global->LDS staging: linear LDS dest (wave-uniform base + lane*16),
// inverse-swizzled GLOBAL source so stored layout == swizzled layout (m173).
template <int NCHUNK>
__device__ __forceinline__ void stage_async(const _Float16* __restrict__ g, int ld,
                                            _Float16* s, int w, int lane) {
    int r_in = lane >> 3;               // 0..7 row within chunk
    int sslot = lane & 7;               // stored 16B slot
    int lslot = sslot ^ r_in;           // logical slot (row&7 == r_in)
#pragma unroll
    for (int q = 0; q < NCHUNK; ++q) {
        int chunk = w * NCHUNK + q;
        int row = chunk * 8 + r_in;
        const _Float16* gp = g + (size_t)row * ld + lslot * 8;
        _Float16* sp = s + chunk * 512;  // wave-uniform
        __builtin_amdgcn_global_load_lds(
            (const __attribute__((address_space(1))) void*)gp,
            (__attribute__((address_space(3))) void*)sp, 16, 0, 0);
    }
}

// ---------------- transpose + fp32->f16 convert:  src[K][N] -> dst[N][K] ----
__global__ __launch_bounds__(256) void k_tcvt(const float* __restrict__ src,
                                              _Float16* __restrict__ dst,
                                              int K, int N) {
    __shared__ float tile[32][33];
    int n0 = blockIdx.x * 32, k0 = blockIdx.y * 32;
    int tx = threadIdx.x, ty = threadIdx.y;
#pragma unroll
    for (int i = 0; i < 32; i += 8)
        tile[ty + i][tx] = src[(size_t)(k0 + ty + i) * N + (n0 + tx)];
    __syncthreads();
#pragma unroll
    for (int i = 0; i < 32; i += 8)
        dst[(size_t)(n0 + ty + i) * K + (k0 + tx)] = (_Float16)tile[tx][ty + i];
}

// ---------------- LayerNorm (fp32 in -> f16 out), one block per row ---------
__global__ __launch_bounds__(256) void k_ln(const float* __restrict__ x,
                                            const float* __restrict__ sc,
                                            const float* __restrict__ sh,
                                            _Float16* __restrict__ out) {
    int row = blockIdx.x;
    int t = threadIdx.x;
    float4 v = ((const float4*)(x + (size_t)row * DIM))[t];
    float sum = v.x + v.y + v.z + v.w;
    float sq  = v.x * v.x + v.y * v.y + v.z * v.z + v.w * v.w;
#pragma unroll
    for (int m = 1; m < 64; m <<= 1) {
        sum += __shfl_xor(sum, m);
        sq  += __shfl_xor(sq, m);
    }
    __shared__ float rs[4], rq[4];
    int w = t >> 6;
    if ((t & 63) == 0) { rs[w] = sum; rq[w] = sq; }
    __syncthreads();
    sum = rs[0] + rs[1] + rs[2] + rs[3];
    sq  = rq[0] + rq[1] + rq[2] + rq[3];
    float mean = sum * (1.0f / DIM);
    float var  = sq * (1.0f / DIM) - mean * mean;
    float rstd = rsqrtf(var + 1e-5f);
    float4 s4 = ((const float4*)sc)[t];
    float4 b4 = ((const float4*)sh)[t];
    f16x4 o;
    o[0] = (_Float16)(s4.x * ((v.x - mean) * rstd) + b4.x);
    o[1] = (_Float16)(s4.y * ((v.y - mean) * rstd) + b4.y);
    o[2] = (_Float16)(s4.z * ((v.z - mean) * rstd) + b4.z);
    o[3] = (_Float16)(s4.w * ((v.w - mean) * rstd) + b4.w);
    ((f16x4*)(out + (size_t)row * DIM))[t] = o;
}

// ---------------- GEMM 128x128, BK=64, async-LDS staged ---------------------
// EPI: 0 = plain -> f16 out; 1 = +bias, gelu -> f16 out
template <int EPI>
__global__ __launch_bounds__(256) void k_gemm(const _Float16* __restrict__ A,
                                              const _Float16* __restrict__ BT,
                                              int M, int N, int K,
                                              _Float16* __restrict__ Ch,
                                              const float* __restrict__ bias) {
    __shared__ _Float16 As[128 * 64];
    __shared__ _Float16 Bs[128 * 64];
    int t = threadIdx.x;
    int m0 = blockIdx.y * 128, n0 = blockIdx.x * 128;
    int lane = t & 63, w = t >> 6;
    int wm = (w >> 1) * 64, wn = (w & 1) * 64;
    int lr = lane & 15, lg = lane >> 4;
    f32x4 acc[4][4];
#pragma unroll
    for (int i = 0; i < 4; ++i)
#pragma unroll
        for (int j = 0; j < 4; ++j) acc[i][j] = (f32x4){0.f, 0.f, 0.f, 0.f};

    const _Float16* Ag = A  + (size_t)m0 * K;
    const _Float16* Bg = BT + (size_t)n0 * K;
    for (int k0 = 0; k0 < K; k0 += 64) {
        stage_async<4>(Ag + k0, K, As, w, lane);
        stage_async<4>(Bg + k0, K, Bs, w, lane);
        __syncthreads();
#pragma unroll
        for (int kk = 0; kk < 2; ++kk) {
            f16x8 a[4], b[4];
#pragma unroll
            for (int i = 0; i < 4; ++i) a[i] = ldsfrag(As, wm + i * 16 + lr, kk * 4 + lg);
#pragma unroll
            for (int j = 0; j < 4; ++j) b[j] = ldsfrag(Bs, wn + j * 16 + lr, kk * 4 + lg);
#pragma unroll
            for (int i = 0; i < 4; ++i)
#pragma unroll
                for (int j = 0; j < 4; ++j)
                    acc[i][j] = __builtin_amdgcn_mfma_f32_16x16x32_f16(a[i], b[j], acc[i][j], 0, 0, 0);
        }
        __syncthreads();
    }
#pragma unroll
    for (int i = 0; i < 4; ++i) {
#pragma unroll
        for (int j = 0; j < 4; ++j) {
            int row = m0 + wm + i * 16 + lg * 4;
            int col = n0 + wn + j * 16 + lr;
#pragma unroll
            for (int r = 0; r < 4; ++r) {
                float v = acc[i][j][r];
                size_t idx = (size_t)(row + r) * N + col;
                if constexpr (EPI == 0) Ch[idx] = (_Float16)v;
                else                    Ch[idx] = (_Float16)geluf(v + bias[col]);
            }
        }
    }
}

// ---------------- GEMM 128x64 tile (for N=1024 outputs), +bias+resid f32 ----
__global__ __launch_bounds__(256) void k_gemm64(const _Float16* __restrict__ A,
                                                const _Float16* __restrict__ BT,
                                                int M, int N, int K,
                                                float* __restrict__ Cf,
                                                const float* __restrict__ bias,
                                                const float* __restrict__ resid) {
    __shared__ _Float16 As[128 * 64];
    __shared__ _Float16 Bs[64 * 64];
    int t = threadIdx.x;
    int m0 = blockIdx.y * 128, n0 = blockIdx.x * 64;
    int lane = t & 63, w = t >> 6;
    int wm = w * 32;
    int lr = lane & 15, lg = lane >> 4;
    f32x4 acc[2][4];
#pragma unroll
    for (int i = 0; i < 2; ++i)
#pragma unroll
        for (int j = 0; j < 4; ++j) acc[i][j] = (f32x4){0.f, 0.f, 0.f, 0.f};

    const _Float16* Ag = A  + (size_t)m0 * K;
    const _Float16* Bg = BT + (size_t)n0 * K;
    for (int k0 = 0; k0 < K; k0 += 64) {
        stage_async<4>(Ag + k0, K, As, w, lane);
        stage_async<2>(Bg + k0, K, Bs, w, lane);
        __syncthreads();
#pragma unroll
        for (int kk = 0; kk < 2; ++kk) {
            f16x8 a[2], b[4];
#pragma unroll
            for (int i = 0; i < 2; ++i) a[i] = ldsfrag(As, wm + i * 16 + lr, kk * 4 + lg);
#pragma unroll
            for (int j = 0; j < 4; ++j) b[j] = ldsfrag(Bs, j * 16 + lr, kk * 4 + lg);
#pragma unroll
            for (int i = 0; i < 2; ++i)
#pragma unroll
                for (int j = 0; j < 4; ++j)
                    acc[i][j] = __builtin_amdgcn_mfma_f32_16x16x32_f16(a[i], b[j], acc[i][j], 0, 0, 0);
        }
        __syncthreads();
    }
#pragma unroll
    for (int i = 0; i < 2; ++i) {
#pragma unroll
        for (int j = 0; j < 4; ++j) {
            int row = m0 + wm + i * 16 + lg * 4;
            int col = n0 + j * 16 + lr;
#pragma unroll
            for (int r = 0; r < 4; ++r) {
                size_t idx = (size_t)(row + r) * N + col;
                Cf[idx] = acc[i][j][r] + bias[col] + resid[idx];
            }
        }
    }
}

// ---------------- Flash attention: 1 wave per (b, h, 32-row q-tile) ---------
// R1's proven barrier-free structure, QBLK=32 -> 2048 waves (2/SIMD) for
// latency hiding. Each wave owns its rows end-to-end; NO barriers anywhere.
__global__ __launch_bounds__(64) void k_attn(const _Float16* __restrict__ QKV,
                                             _Float16* __restrict__ Og) {
    __shared__ _Float16 Vt[64 * 64];  // V^T [d][k], swizzled (8 KB)
    __shared__ _Float16 Ps[32 * 64];  // P[q][k], swizzled (4 KB)
    int lane = threadIdx.x;
    int qt = blockIdx.x, h = blockIdx.y, b = blockIdx.z;
    int q0 = qt * 32;
    int lr = lane & 15, lg = lane >> 4;
    size_t base = (size_t)b * SEQ;
    int cq = h * HDIM, ck = 1024 + h * HDIM, cv = 2048 + h * HDIM;

    // Q fragments in registers, pre-scaled by 1/sqrt(HD)
    f16x8 aq[2][2];
#pragma unroll
    for (int i = 0; i < 2; ++i)
#pragma unroll
        for (int kk = 0; kk < 2; ++kk) {
            f16x8 v = *(const f16x8*)(QKV + (base + q0 + i * 16 + lr) * LDQ + cq + kk * 32 + lg * 8);
#pragma unroll
            for (int e = 0; e < 8; ++e) v[e] = v[e] * (_Float16)0.125f;
            aq[i][kk] = v;
        }

    f32x4 cacc[2][4];
#pragma unroll
    for (int i = 0; i < 2; ++i)
#pragma unroll
        for (int j = 0; j < 4; ++j) cacc[i][j] = (f32x4){0.f, 0.f, 0.f, 0.f};
    float mrun[2][4], lrun[2][4];
#pragma unroll
    for (int i = 0; i < 2; ++i)
#pragma unroll
        for (int r = 0; r < 4; ++r) { mrun[i][r] = -1e30f; lrun[i][r] = 0.f; }

    int ntiles = q0 / 64 + 1;   // 64-wide K/V tiles needed for causal rows
    for (int kt = 0; kt < ntiles; ++kt) {
        int k0 = kt * 64;
        // stage V^T into LDS (scalar transposed writes, swizzled; 2-way = free)
        {
            const _Float16* vr = QKV + (base + k0 + lane) * LDQ + cv;
            int kslot = lane >> 3;
            int kb2 = (lane & 7) * 2;
#pragma unroll
            for (int part = 0; part < 8; ++part) {
                f16x8 v8 = *(const f16x8*)(vr + part * 8);
#pragma unroll
                for (int e = 0; e < 8; ++e) {
                    int d = part * 8 + e;
                    *(_Float16*)((char*)Vt + d * 128 + ((kslot ^ (d & 7)) << 4) + kb2) = v8[e];
                }
            }
        }
        // scores = Q K^T (K fragments straight from global, L2-hot)
        f32x4 sacc[2][4];
#pragma unroll
        for (int i = 0; i < 2; ++i)
#pragma unroll
            for (int j = 0; j < 4; ++j) sacc[i][j] = (f32x4){0.f, 0.f, 0.f, 0.f};
#pragma unroll
        for (int kk = 0; kk < 2; ++kk) {
            f16x8 bk[4];
#pragma unroll
            for (int j = 0; j < 4; ++j)
                bk[j] = *(const f16x8*)(QKV + (base + k0 + j * 16 + lr) * LDQ + ck + kk * 32 + lg * 8);
            __builtin_amdgcn_s_setprio(1);
#pragma unroll
            for (int i = 0; i < 2; ++i)
#pragma unroll
                for (int j = 0; j < 4; ++j)
                    sacc[i][j] = __builtin_amdgcn_mfma_f32_16x16x32_f16(aq[i][kk], bk[j], sacc[i][j], 0, 0, 0);
            __builtin_amdgcn_s_setprio(0);
        }
        // causal mask (last tile only; global coords)
        if (kt == ntiles - 1) {
#pragma unroll
            for (int i = 0; i < 2; ++i)
#pragma unroll
                for (int j = 0; j < 4; ++j)
#pragma unroll
                    for (int r = 0; r < 4; ++r) {
                        int qq = q0 + i * 16 + lg * 4 + r;
                        int kc = k0 + j * 16 + lr;
                        if (kc > qq) sacc[i][j][r] = -1e30f;
                    }
        }
        // online softmax (rows spread over 16 lanes)
#pragma unroll
        for (int i = 0; i < 2; ++i) {
            float mn[4], al[4];
#pragma unroll
            for (int r = 0; r < 4; ++r) {
                float tm = fmaxf(fmaxf(sacc[i][0][r], sacc[i][1][r]),
                                 fmaxf(sacc[i][2][r], sacc[i][3][r]));
#pragma unroll
                for (int msk = 1; msk < 16; msk <<= 1) tm = fmaxf(tm, __shfl_xor(tm, msk));
                float m2 = fmaxf(mrun[i][r], tm);
                al[r] = __expf(mrun[i][r] - m2);
                mrun[i][r] = m2;
                mn[r] = m2;
            }
#pragma unroll
            for (int jd = 0; jd < 4; ++jd)
#pragma unroll
                for (int r = 0; r < 4; ++r) cacc[i][jd][r] *= al[r];
#pragma unroll
            for (int r = 0; r < 4; ++r) {
                float ps = 0.f;
#pragma unroll
                for (int j = 0; j < 4; ++j) {
                    float p = __expf(sacc[i][j][r] - mn[r]);
                    sacc[i][j][r] = p;
                    ps += p;
                }
#pragma unroll
                for (int msk = 1; msk < 16; msk <<= 1) ps += __shfl_xor(ps, msk);
                lrun[i][r] = lrun[i][r] * al[r] + ps;
            }
        }
        // P -> LDS (f16, swizzled A-operand layout)
#pragma unroll
        for (int i = 0; i < 2; ++i)
#pragma unroll
            for (int j = 0; j < 4; ++j) {
                int kc = j * 16 + lr;
                int ks = kc >> 3;
                int kb = (kc & 7) * 2;
#pragma unroll
                for (int r = 0; r < 4; ++r) {
                    int qq = i * 16 + lg * 4 + r;
                    *(_Float16*)((char*)Ps + qq * 128 + ((ks ^ (qq & 7)) << 4) + kb) =
                        (_Float16)sacc[i][j][r];
                }
            }
        // PV accumulate (same-wave LDS RAW; in-order per-wave DS pipe)
#pragma unroll
        for (int kk = 0; kk < 2; ++kk) {
            f16x8 pa[2], bv[4];
#pragma unroll
            for (int i = 0; i < 2; ++i)   pa[i]  = ldsfrag(Ps, i * 16 + lr,  kk * 4 + lg);
#pragma unroll
            for (int jd = 0; jd < 4; ++jd) bv[jd] = ldsfrag(Vt, jd * 16 + lr, kk * 4 + lg);
            __builtin_amdgcn_s_setprio(1);
#pragma unroll
            for (int i = 0; i < 2; ++i)
#pragma unroll
                for (int jd = 0; jd < 4; ++jd)
                    cacc[i][jd] = __builtin_amdgcn_mfma_f32_16x16x32_f16(pa[i], bv[jd], cacc[i][jd], 0, 0, 0);
            __builtin_amdgcn_s_setprio(0);
        }
    }
    // normalize + write ctx in [b*S+s][h*64+d] layout
#pragma unroll
    for (int i = 0; i < 2; ++i)
#pragma unroll
        for (int jd = 0; jd < 4; ++jd)
#pragma unroll
            for (int r = 0; r < 4; ++r) {
                int qq = q0 + i * 16 + lg * 4 + r;
                int d = h * HDIM + jd * 16 + lr;
                Og[(base + qq) * DIM + d] = (_Float16)(cacc[i][jd][r] / lrun[i][r]);
            }
}

// ---------------------------------------------------------------------------
extern "C" void kernel_launch(void* const* d_in, const int* in_sizes, int n_in,
                              void* d_out, int out_size, void* d_ws, size_t ws_size,
                              hipStream_t stream) {
    const float* x    = (const float*)d_in[0];
    const float* WQ   = (const float*)d_in[1];
    const float* WK   = (const float*)d_in[2];
    const float* WV   = (const float*)d_in[3];
    const float* Wo   = (const float*)d_in[4];
    const float* bo   = (const float*)d_in[5];
    const float* W1   = (const float*)d_in[6];
    const float* b1   = (const float*)d_in[7];
    const float* W2   = (const float*)d_in[8];
    const float* b2   = (const float*)d_in[9];
    const float* ln1s = (const float*)d_in[10];
    const float* ln1b = (const float*)d_in[11];
    const float* ln2s = (const float*)d_in[12];
    const float* ln2b = (const float*)d_in[13];
    float* out = (float*)d_out;
    char* ws = (char*)d_ws;
    const size_t MB = 1024 * 1024;
    _Float16* WTqkv = (_Float16*)(ws + 0 * MB);   // [3072][1024] = 6MB
    _Float16* WTo   = (_Float16*)(ws + 6 * MB);
    _Float16* WT1   = (_Float16*)(ws + 8 * MB);   // [4096][1024]
    _Float16* WT2   = (_Float16*)(ws + 16 * MB);  // [1024][4096]
    _Float16* h1    = (_Float16*)(ws + 24 * MB);
    _Float16* qkvb  = (_Float16*)(ws + 32 * MB);  // [4096][3072] = 24MB
    _Float16* ctx   = (_Float16*)(ws + 56 * MB);
    _Float16* h2    = (_Float16*)(ws + 64 * MB);
    _Float16* ff1   = (_Float16*)(ws + 72 * MB);  // [4096][4096] = 32MB
    float*    x2    = (float*)   (ws + 104 * MB); // fp32 residual = 16MB

    dim3 tb(32, 8);
    k_tcvt<<<dim3(32, 32), tb, 0, stream>>>(WQ, WTqkv, 1024, 1024);
    k_tcvt<<<dim3(32, 32), tb, 0, stream>>>(WK, WTqkv + 1024 * 1024, 1024, 1024);
    k_tcvt<<<dim3(32, 32), tb, 0, stream>>>(WV, WTqkv + 2048 * 1024, 1024, 1024);
    k_tcvt<<<dim3(32, 32), tb, 0, stream>>>(Wo, WTo, 1024, 1024);
    k_tcvt<<<dim3(128, 32), tb, 0, stream>>>(W1, WT1, 1024, 4096);
    k_tcvt<<<dim3(32, 128), tb, 0, stream>>>(W2, WT2, 4096, 1024);

    k_ln<<<MTOT, 256, 0, stream>>>(x, ln1s, ln1b, h1);

    // fused QKV: [4096,1024] x [1024,3072] -> [4096,3072]
    k_gemm<0><<<dim3(24, 32), 256, 0, stream>>>(h1, WTqkv, MTOT, LDQ, DIM, qkvb, nullptr);

    k_attn<<<dim3(SEQ / 32, NHEAD, BATCH), 64, 0, stream>>>(qkvb, ctx);

    // x2 = x + ctx @ Wo + bo
    k_gemm64<<<dim3(16, 32), 256, 0, stream>>>(ctx, WTo, MTOT, DIM, DIM, x2, bo, x);

    k_ln<<<MTOT, 256, 0, stream>>>(x2, ln2s, ln2b, h2);

    // ff1 = gelu(h2 @ W1 + b1)
    k_gemm<1><<<dim3(32, 32), 256, 0, stream>>>(h2, WT1, MTOT, DFF, DIM, ff1, b1);

    // out = x2 + ff1 @ W2 + b2
    k_gemm64<<<dim3(16, 32), 256, 0, stream>>>(ff1, WT2, MTOT, DIM, DFF, out, b2, x2);
}